// Round 13
// baseline (214.103 us; speedup 1.0000x reference)
//
#include <hip/hip_runtime.h>
#include <math.h>

#define NE  8
#define HID 256

typedef __attribute__((ext_vector_type(8)))  short short8;
typedef __attribute__((ext_vector_type(16))) float f32x16;

static __device__ __forceinline__ unsigned short f2bf(float f) {
    unsigned int u = __float_as_uint(f);
    return (unsigned short)((u + 0x7FFFu + ((u >> 16) & 1u)) >> 16);
}

static __device__ __forceinline__ short8 pack8(float4 a, float4 b) {
    short8 r;
    r[0] = (short)f2bf(a.x); r[1] = (short)f2bf(a.y);
    r[2] = (short)f2bf(a.z); r[3] = (short)f2bf(a.w);
    r[4] = (short)f2bf(b.x); r[5] = (short)f2bf(b.y);
    r[6] = (short)f2bf(b.z); r[7] = (short)f2bf(b.w);
    return r;
}

// ---------------------------------------------------------------------------
// Kernel 1 (blocks 0..1023): W1 [E][128][256] -> bf16 frag-linear.
//   frag (e, hrt<8, kt<8): [lane][j] = W1[e][kt*16+(lane>>5)*8+j][hrt*32+(lane&31)]
// Block 1024: pk table [e][hrt][q][g][8] f32: j<4 -> b1[h], j>=4 -> W2[h].
// ---------------------------------------------------------------------------
__global__ void prep_w1(const float* __restrict__ W1, const float* __restrict__ b1,
                        const float* __restrict__ W2,
                        unsigned short* __restrict__ wfr, float* __restrict__ pk) {
    if (blockIdx.x < 1024) {
        int f = blockIdx.x * 256 + threadIdx.x;     // 262144 total
        int j   = f & 7;
        int l   = (f >> 3) & 63;
        int kt  = (f >> 9) & 7;
        int hrt = (f >> 12) & 7;
        int e   = f >> 15;
        int k = kt * 16 + ((l >> 5) * 8) + j;
        int h = hrt * 32 + (l & 31);
        wfr[f] = f2bf(W1[((size_t)e * 128 + k) * HID + h]);
    } else {
        for (int i = threadIdx.x; i < 4096; i += 256) {
            int j   = i & 7;
            int g   = (i >> 3) & 1;
            int q   = (i >> 4) & 3;
            int hrt = (i >> 6) & 7;
            int e   = i >> 9;
            int h = hrt * 32 + q * 8 + g * 4 + (j & 3);
            pk[i] = (j < 4) ? b1[e * HID + h] : W2[e * HID + h];
        }
    }
}

// ---------------------------------------------------------------------------
// Kernel 2: gating softmax (exact fp32) + experts_used + per-block partials.
// Also zeroes pred (2-addend atomicAdd determinism on zeroed slots).
// ---------------------------------------------------------------------------
__global__ void gates_kernel(const float* __restrict__ cp,
                             float* __restrict__ gates_out,
                             float* __restrict__ used_out,
                             float* __restrict__ part,
                             float* __restrict__ pred_zero) {
    __shared__ float wp_[4][16];
    int tid = threadIdx.x;
    int b = blockIdx.x * 256 + tid;

    pred_zero[b] = 0.f;

    float g[8];
    {
        const float4* c4 = (const float4*)(cp + (size_t)b * NE);
        float4 a0 = c4[0], a1 = c4[1];
        g[0]=a0.x; g[1]=a0.y; g[2]=a0.z; g[3]=a0.w;
        g[4]=a1.x; g[5]=a1.y; g[6]=a1.z; g[7]=a1.w;
    }
    float m = g[0];
    #pragma unroll
    for (int i = 1; i < 8; ++i) m = fmaxf(m, g[i]);
    float s = 0.f;
    #pragma unroll
    for (int i = 0; i < 8; ++i) { g[i] = __expf(g[i] - m); s += g[i]; }
    float inv = 1.f / s;
    #pragma unroll
    for (int i = 0; i < 8; ++i) g[i] *= inv;

    {
        float4 o0 = make_float4(g[0], g[1], g[2], g[3]);
        float4 o1 = make_float4(g[4], g[5], g[6], g[7]);
        float4* g4 = (float4*)(gates_out + (size_t)b * NE);
        g4[0] = o0; g4[1] = o1;
    }
    float v[16];
    float used = 0.f;
    #pragma unroll
    for (int i = 0; i < 8; ++i) {
        float a = (g[i] > 0.01f) ? 1.f : 0.f;
        used += a;
        v[i] = g[i];
        v[8 + i] = a;
    }
    used_out[b] = used;

    #pragma unroll
    for (int d = 32; d >= 1; d >>= 1)
        #pragma unroll
        for (int i = 0; i < 16; ++i)
            v[i] += __shfl_down(v[i], d, 64);
    int lane = tid & 63, wid = tid >> 6;
    if (lane == 0)
        #pragma unroll
        for (int i = 0; i < 16; ++i) wp_[wid][i] = v[i];
    __syncthreads();
    if (tid < 16)
        part[(size_t)blockIdx.x * 16 + tid] =
            wp_[0][tid] + wp_[1][tid] + wp_[2][tid] + wp_[3][tid];
}

// 512-thread deterministic reduce: 32 partial-threads per output, LDS tree.
__global__ void reduce_kernel(const float* __restrict__ part,
                              float* __restrict__ inf_out,
                              float* __restrict__ cnt_out) {
    __shared__ float red[16][32];
    int t = threadIdx.x;
    int o = t & 15, i = t >> 4;
    float s = 0.f;
    for (int k = i; k < 512; k += 32) s += part[(size_t)k * 16 + o];
    red[o][i] = s;
    __syncthreads();
    if (t < 16) {
        float r = 0.f;
        #pragma unroll
        for (int j = 0; j < 32; ++j) r += red[t][j];
        if (t < 8) inf_out[t] = r;
        else       cnt_out[t - 8] = r;
    }
}

// ---------------------------------------------------------------------------
// Kernel 4: main MoE. 512 blocks x 512 thr (8 waves):
//   tb = blockIdx&255 (512 tokens), grp = blockIdx>>8 (4 experts).
// LDS = EXACTLY 64.0 KB (single-expert W1 buffer, half-pipelined) -> with
// grid 512 this is the FIRST config where 2 blocks/CU can co-reside
// (r3/r9/r12 had grid==CU-count: no partner block existed; r6 had 73.7KB).
// Simple r11-style loop (VGPR 76-proven, no STEP interleave -- r12 showed
// interleave + L2 side-reads = spill). pk (b1/w2) from L2. Co-resident
// blocks are unsynchronized -> mutual barrier/epilogue hiding.
// pred combined via 2-addend atomicAdd on zeroed slots (deterministic).
// ---------------------------------------------------------------------------
#define MFMA_ __builtin_amdgcn_mfma_f32_32x32x16_bf16

__global__ __launch_bounds__(512, 2)
void moe_main(const float* __restrict__ x,
              const unsigned short* __restrict__ wfr,
              const float* __restrict__ pk,
              const float* __restrict__ b2,
              const float* __restrict__ gates,
              float* __restrict__ pred_out) {
    __shared__ unsigned short W1s[8 * 8 * 64 * 8];   // exactly 64 KB

    const int tid  = threadIdx.x;
    const int lane = tid & 63;
    const int wid  = tid >> 6;          // 0..7
    const int g    = lane >> 5;
    const int col  = lane & 31;
    const int tb   = blockIdx.x & 255;
    const int grp  = blockIdx.x >> 8;   // expert group: e in [grp*4, grp*4+4)
    const int tw   = tb * 512 + wid * 64;   // wave token base
    const int e0   = grp * 4;

    // ---- stage both halves of expert e0 (64 KB = 8 waves x (4+4) x 1KB)
    {
        const char* src = (const char*)wfr + (size_t)e0 * 65536 + wid * 4096 + lane * 16;
        char* dst = (char*)&W1s[0] + wid * 4096;
        #pragma unroll
        for (int i = 0; i < 4; ++i) {
            __builtin_amdgcn_global_load_lds(
                (const __attribute__((address_space(1))) unsigned int*)(src + i * 1024),
                (__attribute__((address_space(3))) unsigned int*)(dst + i * 1024),
                16, 0, 0);
            __builtin_amdgcn_global_load_lds(
                (const __attribute__((address_space(1))) unsigned int*)(src + 32768 + i * 1024),
                (__attribute__((address_space(3))) unsigned int*)(dst + 32768 + i * 1024),
                16, 0, 0);
        }
    }

    // ---- x fragments -> registers: frag (tt<2, kt<8): token=tw+tt*32+col,
    //      k = kt*16 + g*8 + j
    short8 xf[2][8];
    #pragma unroll
    for (int tt = 0; tt < 2; ++tt) {
        const float* xr = x + ((size_t)(tw + tt * 32 + col)) * 128 + g * 8;
        #pragma unroll
        for (int kt = 0; kt < 8; ++kt) {
            float4 a = *(const float4*)(xr + kt * 16);
            float4 b = *(const float4*)(xr + kt * 16 + 4);
            xf[tt][kt] = pack8(a, b);
        }
    }

    float pred0 = 0.f, pred1 = 0.f;
    __syncthreads();   // drains: stage(e0 both halves), x loads

    for (int ee = 0; ee < 4; ++ee) {
        const int e = e0 + ee;

        // gate loads hoisted -- latency hides under the MFMA stream
        float gt0 = gates[(size_t)(tw + col) * NE + e];
        float gt1 = gates[(size_t)(tw + 32 + col) * NE + e];
        float bb  = b2[e];

        float yA0 = 0.f, yB0 = 0.f, yA1 = 0.f, yB1 = 0.f;

        // ---------- half A: hrt 0..3 ----------
        for (int hrt = 0; hrt < 4; ++hrt) {
            f32x16 c0 = (f32x16)0.0f, c1 = (f32x16)0.0f;
            #pragma unroll
            for (int kt = 0; kt < 8; ++kt) {
                short8 w = *(const short8*)&W1s[((hrt * 8 + kt) * 64 + lane) * 8];
                c0 = MFMA_(w, xf[0][kt], c0, 0, 0, 0);
                c1 = MFMA_(w, xf[1][kt], c1, 0, 0, 0);
            }
            #pragma unroll
            for (int q = 0; q < 4; ++q) {
                const float* pb = pk + (((e * 8 + hrt) * 4 + q) * 2 + g) * 8;
                float4 b1q = *(const float4*)pb;
                float4 w2q = *(const float4*)(pb + 4);
                yA0 = fmaf(fmaxf(c0[q * 4 + 0] + b1q.x, 0.f), w2q.x, yA0);
                yA1 = fmaf(fmaxf(c1[q * 4 + 0] + b1q.x, 0.f), w2q.x, yA1);
                yB0 = fmaf(fmaxf(c0[q * 4 + 1] + b1q.y, 0.f), w2q.y, yB0);
                yB1 = fmaf(fmaxf(c1[q * 4 + 1] + b1q.y, 0.f), w2q.y, yB1);
                yA0 = fmaf(fmaxf(c0[q * 4 + 2] + b1q.z, 0.f), w2q.z, yA0);
                yA1 = fmaf(fmaxf(c1[q * 4 + 2] + b1q.z, 0.f), w2q.z, yA1);
                yB0 = fmaf(fmaxf(c0[q * 4 + 3] + b1q.w, 0.f), w2q.w, yB0);
                yB1 = fmaf(fmaxf(c1[q * 4 + 3] + b1q.w, 0.f), w2q.w, yB1);
            }
        }

        __syncthreads();   // all reads of half A done
        if (ee < 3) {      // stage half A <- expert e+1 (overlaps half-B compute;
                           // drained at the barrier after half B)
            const char* src = (const char*)wfr + (size_t)(e + 1) * 65536
                            + (size_t)wid * 4096 + lane * 16;
            char* dst = (char*)&W1s[0] + wid * 4096;
            #pragma unroll
            for (int i = 0; i < 4; ++i)
                __builtin_amdgcn_global_load_lds(
                    (const __attribute__((address_space(1))) unsigned int*)(src + i * 1024),
                    (__attribute__((address_space(3))) unsigned int*)(dst + i * 1024),
                    16, 0, 0);
        }

        // ---------- half B: hrt 4..7 ----------
        for (int hrt = 4; hrt < 8; ++hrt) {
            f32x16 c0 = (f32x16)0.0f, c1 = (f32x16)0.0f;
            #pragma unroll
            for (int kt = 0; kt < 8; ++kt) {
                short8 w = *(const short8*)&W1s[((hrt * 8 + kt) * 64 + lane) * 8];
                c0 = MFMA_(w, xf[0][kt], c0, 0, 0, 0);
                c1 = MFMA_(w, xf[1][kt], c1, 0, 0, 0);
            }
            #pragma unroll
            for (int q = 0; q < 4; ++q) {
                const float* pb = pk + (((e * 8 + hrt) * 4 + q) * 2 + g) * 8;
                float4 b1q = *(const float4*)pb;
                float4 w2q = *(const float4*)(pb + 4);
                yA0 = fmaf(fmaxf(c0[q * 4 + 0] + b1q.x, 0.f), w2q.x, yA0);
                yA1 = fmaf(fmaxf(c1[q * 4 + 0] + b1q.x, 0.f), w2q.x, yA1);
                yB0 = fmaf(fmaxf(c0[q * 4 + 1] + b1q.y, 0.f), w2q.y, yB0);
                yB1 = fmaf(fmaxf(c1[q * 4 + 1] + b1q.y, 0.f), w2q.y, yB1);
                yA0 = fmaf(fmaxf(c0[q * 4 + 2] + b1q.z, 0.f), w2q.z, yA0);
                yA1 = fmaf(fmaxf(c1[q * 4 + 2] + b1q.z, 0.f), w2q.z, yA1);
                yB0 = fmaf(fmaxf(c0[q * 4 + 3] + b1q.w, 0.f), w2q.w, yB0);
                yB1 = fmaf(fmaxf(c1[q * 4 + 3] + b1q.w, 0.f), w2q.w, yB1);
            }
        }

        // fold halves, sigmoid, gate-weight
        {
            float ye0 = yA0 + yB0;
            float ye1 = yA1 + yB1;
            float s0 = ye0 + __shfl_xor(ye0, 32, 64) + bb;
            float s1 = ye1 + __shfl_xor(ye1, 32, 64) + bb;
            float yv0 = 1.f / (1.f + __expf(-s0));
            float yv1 = 1.f / (1.f + __expf(-s1));
            pred0 = fmaf(gt0, yv0, pred0);
            pred1 = fmaf(gt1, yv1, pred1);
        }

        __syncthreads();   // half-B reads done; drains stage-halfA(e+1)
        if (ee < 3) {      // stage half B <- expert e+1 (overlaps next half-A)
            const char* src = (const char*)wfr + (size_t)(e + 1) * 65536 + 32768
                            + (size_t)wid * 4096 + lane * 16;
            char* dst = (char*)&W1s[0] + 32768 + wid * 4096;
            #pragma unroll
            for (int i = 0; i < 4; ++i)
                __builtin_amdgcn_global_load_lds(
                    (const __attribute__((address_space(1))) unsigned int*)(src + i * 1024),
                    (__attribute__((address_space(3))) unsigned int*)(dst + i * 1024),
                    16, 0, 0);
        }
    }

    // combine the two expert-group partials (exactly 2 addends on zeroed slot
    // -> bit-deterministic)
    if (lane < 32) {
        atomicAdd(&pred_out[tw + col],      pred0);
        atomicAdd(&pred_out[tw + 32 + col], pred1);
    }
}

// ---------------------------------------------------------------------------
extern "C" void kernel_launch(void* const* d_in, const int* in_sizes, int n_in,
                              void* d_out, int out_size, void* d_ws, size_t ws_size,
                              hipStream_t stream) {
    (void)in_sizes; (void)n_in; (void)out_size; (void)ws_size;
    const float* x  = (const float*)d_in[0];
    const float* cp = (const float*)d_in[1];
    const float* W1 = (const float*)d_in[2];
    const float* b1 = (const float*)d_in[3];
    const float* W2 = (const float*)d_in[4];
    const float* b2 = (const float*)d_in[5];

    float* out   = (float*)d_out;
    float* pred  = out;                       // [131072]
    float* gates = out + 131072;              // [131072*8]
    float* used  = out + 1179648;             // [131072]
    float* inf   = out + 1310720;             // [8]
    float* cnt   = out + 1310728;             // [8]

    unsigned short* wfrag = (unsigned short*)d_ws;           // 512 KB frag W1
    float* pk   = (float*)((char*)d_ws + 524288);            // 16 KB b1/w2 table
    float* part = (float*)((char*)d_ws + 540672);            // 32 KB partials

    prep_w1<<<dim3(1025), dim3(256), 0, stream>>>(W1, b1, W2, wfrag, pk);
    gates_kernel<<<dim3(512), dim3(256), 0, stream>>>(cp, gates, used, part, pred);
    reduce_kernel<<<dim3(1), dim3(512), 0, stream>>>(part, inf, cnt);
    moe_main<<<dim3(512), dim3(512), 0, stream>>>(x, wfrag, pk, b2, gates, pred);
}

// Round 14
// 105.031 us; speedup vs baseline: 2.0385x; 2.0385x over previous
//
#include <hip/hip_runtime.h>
#include <math.h>

#define NE  8
#define HID 256

typedef __attribute__((ext_vector_type(8)))  short short8;
typedef __attribute__((ext_vector_type(8)))  unsigned short ushort8;
typedef __attribute__((ext_vector_type(16))) float f32x16;

static __device__ __forceinline__ unsigned short f2bf(float f) {
    unsigned int u = __float_as_uint(f);
    return (unsigned short)((u + 0x7FFFu + ((u >> 16) & 1u)) >> 16);
}
static __device__ __forceinline__ float bfh(unsigned short u) {
    return __uint_as_float(((unsigned int)u) << 16);
}

static __device__ __forceinline__ short8 pack8(float4 a, float4 b) {
    short8 r;
    r[0] = (short)f2bf(a.x); r[1] = (short)f2bf(a.y);
    r[2] = (short)f2bf(a.z); r[3] = (short)f2bf(a.w);
    r[4] = (short)f2bf(b.x); r[5] = (short)f2bf(b.y);
    r[6] = (short)f2bf(b.z); r[7] = (short)f2bf(b.w);
    return r;
}

// ---------------------------------------------------------------------------
// Kernel 1 (blocks 0..1023): W1 [E][128][256] -> bf16 frag-linear.
//   frag (e, hrt<8, kt<8): [lane][j] = W1[e][kt*16+(lane>>5)*8+j][hrt*32+(lane&31)]
// Block 1024: pkh table, 512 entries x 16B: entry (e,hrt,q,g) =
//   { b1[h..h+3], W2[h..h+3] } as bf16x8, h = hrt*32+q*8+g*4.
// ---------------------------------------------------------------------------
__global__ void prep_w1(const float* __restrict__ W1, const float* __restrict__ b1,
                        const float* __restrict__ W2,
                        unsigned short* __restrict__ wfr,
                        unsigned short* __restrict__ pkh) {
    if (blockIdx.x < 1024) {
        int f = blockIdx.x * 256 + threadIdx.x;     // 262144 total
        int j   = f & 7;
        int l   = (f >> 3) & 63;
        int kt  = (f >> 9) & 7;
        int hrt = (f >> 12) & 7;
        int e   = f >> 15;
        int k = kt * 16 + ((l >> 5) * 8) + j;
        int h = hrt * 32 + (l & 31);
        wfr[f] = f2bf(W1[((size_t)e * 128 + k) * HID + h]);
    } else {
        for (int ent = threadIdx.x; ent < 512; ent += 256) {
            int g   = ent & 1;
            int q   = (ent >> 1) & 3;
            int hrt = (ent >> 3) & 7;
            int e   = ent >> 6;
            int h = hrt * 32 + q * 8 + g * 4;
            ushort8 v;
            #pragma unroll
            for (int j = 0; j < 4; ++j) {
                v[j]     = f2bf(b1[e * HID + h + j]);
                v[4 + j] = f2bf(W2[e * HID + h + j]);
            }
            *(ushort8*)&pkh[(size_t)ent * 8] = v;
        }
    }
}

// ---------------------------------------------------------------------------
// Kernel 2: gating softmax (exact fp32) + experts_used + per-block partials.
// Also zeroes pred (2-addend atomicAdd determinism on zeroed slots).
// ---------------------------------------------------------------------------
__global__ void gates_kernel(const float* __restrict__ cp,
                             float* __restrict__ gates_out,
                             float* __restrict__ used_out,
                             float* __restrict__ part,
                             float* __restrict__ pred_zero) {
    __shared__ float wp_[4][16];
    int tid = threadIdx.x;
    int b = blockIdx.x * 256 + tid;

    pred_zero[b] = 0.f;

    float g[8];
    {
        const float4* c4 = (const float4*)(cp + (size_t)b * NE);
        float4 a0 = c4[0], a1 = c4[1];
        g[0]=a0.x; g[1]=a0.y; g[2]=a0.z; g[3]=a0.w;
        g[4]=a1.x; g[5]=a1.y; g[6]=a1.z; g[7]=a1.w;
    }
    float m = g[0];
    #pragma unroll
    for (int i = 1; i < 8; ++i) m = fmaxf(m, g[i]);
    float s = 0.f;
    #pragma unroll
    for (int i = 0; i < 8; ++i) { g[i] = __expf(g[i] - m); s += g[i]; }
    float inv = 1.f / s;
    #pragma unroll
    for (int i = 0; i < 8; ++i) g[i] *= inv;

    {
        float4 o0 = make_float4(g[0], g[1], g[2], g[3]);
        float4 o1 = make_float4(g[4], g[5], g[6], g[7]);
        float4* g4 = (float4*)(gates_out + (size_t)b * NE);
        g4[0] = o0; g4[1] = o1;
    }
    float v[16];
    float used = 0.f;
    #pragma unroll
    for (int i = 0; i < 8; ++i) {
        float a = (g[i] > 0.01f) ? 1.f : 0.f;
        used += a;
        v[i] = g[i];
        v[8 + i] = a;
    }
    used_out[b] = used;

    #pragma unroll
    for (int d = 32; d >= 1; d >>= 1)
        #pragma unroll
        for (int i = 0; i < 16; ++i)
            v[i] += __shfl_down(v[i], d, 64);
    int lane = tid & 63, wid = tid >> 6;
    if (lane == 0)
        #pragma unroll
        for (int i = 0; i < 16; ++i) wp_[wid][i] = v[i];
    __syncthreads();
    if (tid < 16)
        part[(size_t)blockIdx.x * 16 + tid] =
            wp_[0][tid] + wp_[1][tid] + wp_[2][tid] + wp_[3][tid];
}

// 512-thread deterministic reduce: 32 partial-threads per output, LDS tree.
__global__ void reduce_kernel(const float* __restrict__ part,
                              float* __restrict__ inf_out,
                              float* __restrict__ cnt_out) {
    __shared__ float red[16][32];
    int t = threadIdx.x;
    int o = t & 15, i = t >> 4;
    float s = 0.f;
    for (int k = i; k < 512; k += 32) s += part[(size_t)k * 16 + o];
    red[o][i] = s;
    __syncthreads();
    if (t < 16) {
        float r = 0.f;
        #pragma unroll
        for (int j = 0; j < 32; ++j) r += red[t][j];
        if (t < 8) inf_out[t] = r;
        else       cnt_out[t - 8] = r;
    }
}

// ---------------------------------------------------------------------------
// Kernel 4: main MoE. 512 blocks x 512 thr (8 waves):
//   tb = blockIdx&255 (512 tokens), eg = blockIdx>>8 (4 experts).
// LDS = 36 KB total: 2 x 16KB W1 chunk ping-pong (chunk = 2 hrt) + 4KB
// bf16-packed pk slice. First clean co-residency test (needs 72KB/CU).
// All epilogue side-reads from LDS (r13 lesson: global loads in the inner
// loop get hoisted -> spill; LDS reads don't). 16-chunk pipeline:
//   compute chunk c from buf[c&1]; barrier; stage chunk c+2 into buf[c&1].
// pred combined via 2-addend atomicAdd on zeroed slots (deterministic).
// ---------------------------------------------------------------------------
#define MFMA_ __builtin_amdgcn_mfma_f32_32x32x16_bf16

__global__ __launch_bounds__(512, 2)
void moe_main(const float* __restrict__ x,
              const unsigned short* __restrict__ wfr,
              const unsigned short* __restrict__ pkh,
              const float* __restrict__ b2,
              const float* __restrict__ gates,
              float* __restrict__ pred_out) {
    __shared__ unsigned short W1s[2][2 * 8 * 64 * 8];   // 2 x 16 KB
    __shared__ unsigned short pkhs[256 * 8];            // 4 KB (eg slice)

    const int tid  = threadIdx.x;
    const int lane = tid & 63;
    const int wid  = tid >> 6;          // 0..7
    const int g    = lane >> 5;
    const int col  = lane & 31;
    const int tb   = blockIdx.x & 255;
    const int eg   = blockIdx.x >> 8;   // expert group: e in [eg*4, eg*4+4)
    const int tw   = tb * 512 + wid * 64;   // wave token base
    const int e0   = eg * 4;

    // ---- stage chunks 0 and 1 (each 16 KB = 8 waves x 2 x 1KB)
    #pragma unroll
    for (int c = 0; c < 2; ++c) {
        const char* src = (const char*)wfr + (size_t)e0 * 65536 + c * 16384
                        + wid * 2048 + lane * 16;
        char* dst = (char*)&W1s[c][0] + wid * 2048;
        #pragma unroll
        for (int i = 0; i < 2; ++i)
            __builtin_amdgcn_global_load_lds(
                (const __attribute__((address_space(1))) unsigned int*)(src + i * 1024),
                (__attribute__((address_space(3))) unsigned int*)(dst + i * 1024),
                16, 0, 0);
    }
    // ---- pkh eg-slice -> LDS (4 KB, 256 x 16B)
    if (tid < 256)
        ((uint4*)pkhs)[tid] = ((const uint4*)((const char*)pkh + (size_t)eg * 4096))[tid];

    // ---- x fragments -> registers: frag (tt<2, kt<8): token=tw+tt*32+col,
    //      k = kt*16 + g*8 + j
    short8 xf[2][8];
    #pragma unroll
    for (int tt = 0; tt < 2; ++tt) {
        const float* xr = x + ((size_t)(tw + tt * 32 + col)) * 128 + g * 8;
        #pragma unroll
        for (int kt = 0; kt < 8; ++kt) {
            float4 a = *(const float4*)(xr + kt * 16);
            float4 b = *(const float4*)(xr + kt * 16 + 4);
            xf[tt][kt] = pack8(a, b);
        }
    }

    float pred0 = 0.f, pred1 = 0.f;
    __syncthreads();   // drains: stage(c0,c1), pkhs, x loads

    for (int ee = 0; ee < 4; ++ee) {
        const int e = e0 + ee;

        // hoisted per-expert scalars (hide under MFMA stream)
        float gt0 = gates[(size_t)(tw + col) * NE + e];
        float gt1 = gates[(size_t)(tw + 32 + col) * NE + e];
        float bb  = b2[e];

        float ye0 = 0.f, ye1 = 0.f;

        for (int cq = 0; cq < 4; ++cq) {        // chunk = 2 hrt
            const int bsel = cq & 1;            // ee*4 even -> (c&1)==(cq&1)
            #pragma unroll
            for (int hr2 = 0; hr2 < 2; ++hr2) {
                const int hrt = cq * 2 + hr2;
                f32x16 c0 = (f32x16)0.0f, c1 = (f32x16)0.0f;
                #pragma unroll
                for (int kt = 0; kt < 8; ++kt) {
                    short8 w = *(const short8*)&W1s[bsel][((hr2 * 8 + kt) * 64 + lane) * 8];
                    c0 = MFMA_(w, xf[0][kt], c0, 0, 0, 0);
                    c1 = MFMA_(w, xf[1][kt], c1, 0, 0, 0);
                }
                // epilogue from LDS bf16 table: h = hrt*32 + q*8 + g*4 + i
                #pragma unroll
                for (int q = 0; q < 4; ++q) {
                    ushort8 pv = *(const ushort8*)&pkhs[(ee * 64 + hrt * 8 + q * 2 + g) * 8];
                    ye0 = fmaf(fmaxf(c0[q * 4 + 0] + bfh(pv[0]), 0.f), bfh(pv[4]), ye0);
                    ye1 = fmaf(fmaxf(c1[q * 4 + 0] + bfh(pv[0]), 0.f), bfh(pv[4]), ye1);
                    ye0 = fmaf(fmaxf(c0[q * 4 + 1] + bfh(pv[1]), 0.f), bfh(pv[5]), ye0);
                    ye1 = fmaf(fmaxf(c1[q * 4 + 1] + bfh(pv[1]), 0.f), bfh(pv[5]), ye1);
                    ye0 = fmaf(fmaxf(c0[q * 4 + 2] + bfh(pv[2]), 0.f), bfh(pv[6]), ye0);
                    ye1 = fmaf(fmaxf(c1[q * 4 + 2] + bfh(pv[2]), 0.f), bfh(pv[6]), ye1);
                    ye0 = fmaf(fmaxf(c0[q * 4 + 3] + bfh(pv[3]), 0.f), bfh(pv[7]), ye0);
                    ye1 = fmaf(fmaxf(c1[q * 4 + 3] + bfh(pv[3]), 0.f), bfh(pv[7]), ye1);
                }
            }

            __syncthreads();   // reads of buf[bsel] done; prior stages drained
            const int c = ee * 4 + cq;
            if (c + 2 < 16) {  // stage chunk c+2 into buf[(c+2)&1] == buf[bsel]
                const int cn = c + 2;
                const char* src = (const char*)wfr
                                + (size_t)(e0 + (cn >> 2)) * 65536 + (cn & 3) * 16384
                                + wid * 2048 + lane * 16;
                char* dst = (char*)&W1s[bsel][0] + wid * 2048;
                #pragma unroll
                for (int i = 0; i < 2; ++i)
                    __builtin_amdgcn_global_load_lds(
                        (const __attribute__((address_space(1))) unsigned int*)(src + i * 1024),
                        (__attribute__((address_space(3))) unsigned int*)(dst + i * 1024),
                        16, 0, 0);
            }
        }

        // fold halves, sigmoid, gate-weight
        {
            float s0 = ye0 + __shfl_xor(ye0, 32, 64) + bb;
            float s1 = ye1 + __shfl_xor(ye1, 32, 64) + bb;
            float yv0 = 1.f / (1.f + __expf(-s0));
            float yv1 = 1.f / (1.f + __expf(-s1));
            pred0 = fmaf(gt0, yv0, pred0);
            pred1 = fmaf(gt1, yv1, pred1);
        }
    }

    // combine the two expert-group partials (exactly 2 addends on zeroed slot
    // -> bit-deterministic)
    if (lane < 32) {
        atomicAdd(&pred_out[tw + col],      pred0);
        atomicAdd(&pred_out[tw + 32 + col], pred1);
    }
}

// ---------------------------------------------------------------------------
extern "C" void kernel_launch(void* const* d_in, const int* in_sizes, int n_in,
                              void* d_out, int out_size, void* d_ws, size_t ws_size,
                              hipStream_t stream) {
    (void)in_sizes; (void)n_in; (void)out_size; (void)ws_size;
    const float* x  = (const float*)d_in[0];
    const float* cp = (const float*)d_in[1];
    const float* W1 = (const float*)d_in[2];
    const float* b1 = (const float*)d_in[3];
    const float* W2 = (const float*)d_in[4];
    const float* b2 = (const float*)d_in[5];

    float* out   = (float*)d_out;
    float* pred  = out;                       // [131072]
    float* gates = out + 131072;              // [131072*8]
    float* used  = out + 1179648;             // [131072]
    float* inf   = out + 1310720;             // [8]
    float* cnt   = out + 1310728;             // [8]

    unsigned short* wfrag = (unsigned short*)d_ws;            // 512 KB frag W1
    unsigned short* pkh = (unsigned short*)((char*)d_ws + 524288);  // 8 KB bf16 b1/w2
    float* part = (float*)((char*)d_ws + 532480);             // 32 KB partials

    prep_w1<<<dim3(1025), dim3(256), 0, stream>>>(W1, b1, W2, wfrag, pkh);
    gates_kernel<<<dim3(512), dim3(256), 0, stream>>>(cp, gates, used, part, pred);
    reduce_kernel<<<dim3(1), dim3(512), 0, stream>>>(part, inf, cnt);
    moe_main<<<dim3(512), dim3(512), 0, stream>>>(x, wfrag, pkh, b2, gates, pred);
}

// Round 15
// 90.630 us; speedup vs baseline: 2.3624x; 1.1589x over previous
//
#include <hip/hip_runtime.h>
#include <math.h>

#define NE  8
#define HID 256

typedef __attribute__((ext_vector_type(8)))  short short8;
typedef __attribute__((ext_vector_type(8)))  unsigned short ushort8;
typedef __attribute__((ext_vector_type(16))) float f32x16;

static __device__ __forceinline__ unsigned short f2bf(float f) {
    unsigned int u = __float_as_uint(f);
    return (unsigned short)((u + 0x7FFFu + ((u >> 16) & 1u)) >> 16);
}
static __device__ __forceinline__ float bfh(unsigned short u) {
    return __uint_as_float(((unsigned int)u) << 16);
}

static __device__ __forceinline__ short8 pack8(float4 a, float4 b) {
    short8 r;
    r[0] = (short)f2bf(a.x); r[1] = (short)f2bf(a.y);
    r[2] = (short)f2bf(a.z); r[3] = (short)f2bf(a.w);
    r[4] = (short)f2bf(b.x); r[5] = (short)f2bf(b.y);
    r[6] = (short)f2bf(b.z); r[7] = (short)f2bf(b.w);
    return r;
}

// ---------------------------------------------------------------------------
// Kernel 1 (blocks 0..1023): W1 [E][128][256] -> bf16 frag-linear.
//   frag (e, hrt<8, kt<8): [lane][j] = W1[e][kt*16+(lane>>5)*8+j][hrt*32+(lane&31)]
// Block 1024: pkh table, 512 entries x 16B: entry (e,hrt,q,g) =
//   { b1[h..h+3], W2[h..h+3] } as bf16x8, h = hrt*32+q*8+g*4.
// ---------------------------------------------------------------------------
__global__ void prep_w1(const float* __restrict__ W1, const float* __restrict__ b1,
                        const float* __restrict__ W2,
                        unsigned short* __restrict__ wfr,
                        unsigned short* __restrict__ pkh) {
    if (blockIdx.x < 1024) {
        int f = blockIdx.x * 256 + threadIdx.x;     // 262144 total
        int j   = f & 7;
        int l   = (f >> 3) & 63;
        int kt  = (f >> 9) & 7;
        int hrt = (f >> 12) & 7;
        int e   = f >> 15;
        int k = kt * 16 + ((l >> 5) * 8) + j;
        int h = hrt * 32 + (l & 31);
        wfr[f] = f2bf(W1[((size_t)e * 128 + k) * HID + h]);
    } else {
        for (int ent = threadIdx.x; ent < 512; ent += 256) {
            int g   = ent & 1;
            int q   = (ent >> 1) & 3;
            int hrt = (ent >> 3) & 7;
            int e   = ent >> 6;
            int h = hrt * 32 + q * 8 + g * 4;
            ushort8 v;
            #pragma unroll
            for (int j = 0; j < 4; ++j) {
                v[j]     = f2bf(b1[e * HID + h + j]);
                v[4 + j] = f2bf(W2[e * HID + h + j]);
            }
            *(ushort8*)&pkh[(size_t)ent * 8] = v;
        }
    }
}

// ---------------------------------------------------------------------------
// Kernel 2: gating softmax (exact fp32) + experts_used + per-block partials
// ---------------------------------------------------------------------------
__global__ void gates_kernel(const float* __restrict__ cp,
                             float* __restrict__ gates_out,
                             float* __restrict__ used_out,
                             float* __restrict__ part) {
    __shared__ float wp_[4][16];
    int tid = threadIdx.x;
    int b = blockIdx.x * 256 + tid;

    float g[8];
    {
        const float4* c4 = (const float4*)(cp + (size_t)b * NE);
        float4 a0 = c4[0], a1 = c4[1];
        g[0]=a0.x; g[1]=a0.y; g[2]=a0.z; g[3]=a0.w;
        g[4]=a1.x; g[5]=a1.y; g[6]=a1.z; g[7]=a1.w;
    }
    float m = g[0];
    #pragma unroll
    for (int i = 1; i < 8; ++i) m = fmaxf(m, g[i]);
    float s = 0.f;
    #pragma unroll
    for (int i = 0; i < 8; ++i) { g[i] = __expf(g[i] - m); s += g[i]; }
    float inv = 1.f / s;
    #pragma unroll
    for (int i = 0; i < 8; ++i) g[i] *= inv;

    {
        float4 o0 = make_float4(g[0], g[1], g[2], g[3]);
        float4 o1 = make_float4(g[4], g[5], g[6], g[7]);
        float4* g4 = (float4*)(gates_out + (size_t)b * NE);
        g4[0] = o0; g4[1] = o1;
    }
    float v[16];
    float used = 0.f;
    #pragma unroll
    for (int i = 0; i < 8; ++i) {
        float a = (g[i] > 0.01f) ? 1.f : 0.f;
        used += a;
        v[i] = g[i];
        v[8 + i] = a;
    }
    used_out[b] = used;

    #pragma unroll
    for (int d = 32; d >= 1; d >>= 1)
        #pragma unroll
        for (int i = 0; i < 16; ++i)
            v[i] += __shfl_down(v[i], d, 64);
    int lane = tid & 63, wid = tid >> 6;
    if (lane == 0)
        #pragma unroll
        for (int i = 0; i < 16; ++i) wp_[wid][i] = v[i];
    __syncthreads();
    if (tid < 16)
        part[(size_t)blockIdx.x * 16 + tid] =
            wp_[0][tid] + wp_[1][tid] + wp_[2][tid] + wp_[3][tid];
}

// 512-thread deterministic reduce: 32 partial-threads per output, LDS tree.
__global__ void reduce_kernel(const float* __restrict__ part,
                              float* __restrict__ inf_out,
                              float* __restrict__ cnt_out) {
    __shared__ float red[16][32];
    int t = threadIdx.x;
    int o = t & 15, i = t >> 4;
    float s = 0.f;
    for (int k = i; k < 512; k += 32) s += part[(size_t)k * 16 + o];
    red[o][i] = s;
    __syncthreads();
    if (t < 16) {
        float r = 0.f;
        #pragma unroll
        for (int j = 0; j < 32; ++j) r += red[t][j];
        if (t < 8) inf_out[t] = r;
        else       cnt_out[t - 8] = r;
    }
}

// ---------------------------------------------------------------------------
// Kernel 4: main MoE = r9 champion + (a) bf16-packed pkh table in LDS
// (halves epilogue LDS traffic; LDS/expert 12.2k->9.1k cyc) + (b) per-wave
// hrt rotation (wave w starts at hrt=w&7) to break the post-barrier convoy
// where all waves burst ds_reads of the same region simultaneously.
// 256 blocks x 512 thr (8 waves, 64 tokens each), 2x64KB W1 dbuf, ONE
// barrier per expert, epilogue of hrt-1 interleaved into MFMAs of hrt
// (named acc ping-pong). Direct pred stores (deterministic, no atomics).
// ---------------------------------------------------------------------------
#define MFMA_ __builtin_amdgcn_mfma_f32_32x32x16_bf16

// MFMAs of HRT into C0/C1 interleaved with epilogue of PH (acc P0/P1).
// HRT/PH are runtime (rotated per wave).
#define STEP(HRT, C0, C1, P0, P1, PH) { \
    ushort8 pv; \
    const unsigned short* wb = &W1s[p][(HRT) * 4096]; \
    const unsigned short* pb = &pkhs[((e8 + (PH)) * 8 + g) * 8]; \
    _Pragma("unroll") \
    for (int kt = 0; kt < 8; ++kt) { \
        short8 w = *(const short8*)&wb[(kt * 64 + lane) * 8]; \
        C0 = MFMA_(w, xf[0][kt], C0, 0, 0, 0); \
        C1 = MFMA_(w, xf[1][kt], C1, 0, 0, 0); \
        int q = kt >> 1; \
        if ((kt & 1) == 0) { \
            pv = *(const ushort8*)&pb[q * 16]; \
            ye0 = fmaf(fmaxf(P0[q * 4 + 0] + bfh(pv[0]), 0.f), bfh(pv[4]), ye0); \
            ye1 = fmaf(fmaxf(P1[q * 4 + 0] + bfh(pv[0]), 0.f), bfh(pv[4]), ye1); \
            ye0 = fmaf(fmaxf(P0[q * 4 + 1] + bfh(pv[1]), 0.f), bfh(pv[5]), ye0); \
            ye1 = fmaf(fmaxf(P1[q * 4 + 1] + bfh(pv[1]), 0.f), bfh(pv[5]), ye1); \
        } else { \
            ye0 = fmaf(fmaxf(P0[q * 4 + 2] + bfh(pv[2]), 0.f), bfh(pv[6]), ye0); \
            ye1 = fmaf(fmaxf(P1[q * 4 + 2] + bfh(pv[2]), 0.f), bfh(pv[6]), ye1); \
            ye0 = fmaf(fmaxf(P0[q * 4 + 3] + bfh(pv[3]), 0.f), bfh(pv[7]), ye0); \
            ye1 = fmaf(fmaxf(P1[q * 4 + 3] + bfh(pv[3]), 0.f), bfh(pv[7]), ye1); \
        } \
    } }

#define STEP_NOEPI(HRT, C0, C1) { \
    const unsigned short* wb = &W1s[p][(HRT) * 4096]; \
    _Pragma("unroll") \
    for (int kt = 0; kt < 8; ++kt) { \
        short8 w = *(const short8*)&wb[(kt * 64 + lane) * 8]; \
        C0 = MFMA_(w, xf[0][kt], C0, 0, 0, 0); \
        C1 = MFMA_(w, xf[1][kt], C1, 0, 0, 0); \
    } }

#define EPI_TAIL(P0, P1, PH) { \
    const unsigned short* pb = &pkhs[((e8 + (PH)) * 8 + g) * 8]; \
    _Pragma("unroll") \
    for (int q = 0; q < 4; ++q) { \
        ushort8 pv = *(const ushort8*)&pb[q * 16]; \
        ye0 = fmaf(fmaxf(P0[q * 4 + 0] + bfh(pv[0]), 0.f), bfh(pv[4]), ye0); \
        ye1 = fmaf(fmaxf(P1[q * 4 + 0] + bfh(pv[0]), 0.f), bfh(pv[4]), ye1); \
        ye0 = fmaf(fmaxf(P0[q * 4 + 1] + bfh(pv[1]), 0.f), bfh(pv[5]), ye0); \
        ye1 = fmaf(fmaxf(P1[q * 4 + 1] + bfh(pv[1]), 0.f), bfh(pv[5]), ye1); \
        ye0 = fmaf(fmaxf(P0[q * 4 + 2] + bfh(pv[2]), 0.f), bfh(pv[6]), ye0); \
        ye1 = fmaf(fmaxf(P1[q * 4 + 2] + bfh(pv[2]), 0.f), bfh(pv[6]), ye1); \
        ye0 = fmaf(fmaxf(P0[q * 4 + 3] + bfh(pv[3]), 0.f), bfh(pv[7]), ye0); \
        ye1 = fmaf(fmaxf(P1[q * 4 + 3] + bfh(pv[3]), 0.f), bfh(pv[7]), ye1); \
    } }

__global__ __launch_bounds__(512, 2)
void moe_main(const float* __restrict__ x,
              const unsigned short* __restrict__ wfr,
              const unsigned short* __restrict__ pkh,
              const float* __restrict__ b2,
              const float* __restrict__ gates,
              float* __restrict__ pred_out) {
    __shared__ unsigned short W1s[2][8 * 8 * 64 * 8];   // 2 x 64 KB
    __shared__ unsigned short pkhs[512 * 8];            // 8 KB (all experts)

    const int tid  = threadIdx.x;
    const int lane = tid & 63;
    const int wid  = tid >> 6;          // 0..7
    const int g    = lane >> 5;
    const int col  = lane & 31;
    const int tw   = blockIdx.x * 512 + wid * 64;   // wave token base
    const int rot  = wid & 7;           // per-wave hrt rotation

    // ---- stage expert 0 into buf 0 (64 KB = 8 waves x 8 x 1KB)
    {
        const char* src = (const char*)wfr + (size_t)wid * 8192 + lane * 16;
        char* dst = (char*)&W1s[0][0] + wid * 8192;
        #pragma unroll
        for (int i = 0; i < 8; ++i)
            __builtin_amdgcn_global_load_lds(
                (const __attribute__((address_space(1))) unsigned int*)(src + i * 1024),
                (__attribute__((address_space(3))) unsigned int*)(dst + i * 1024),
                16, 0, 0);
    }
    // ---- pkh table -> LDS (8 KB = 512 x 16B)
    ((uint4*)pkhs)[tid] = ((const uint4*)pkh)[tid];

    // ---- x fragments -> registers: frag (tt<2, kt<8): token=tw+tt*32+col,
    //      k = kt*16 + g*8 + j
    short8 xf[2][8];
    #pragma unroll
    for (int tt = 0; tt < 2; ++tt) {
        const float* xr = x + ((size_t)(tw + tt * 32 + col)) * 128 + g * 8;
        #pragma unroll
        for (int kt = 0; kt < 8; ++kt) {
            float4 a = *(const float4*)(xr + kt * 16);
            float4 b = *(const float4*)(xr + kt * 16 + 4);
            xf[tt][kt] = pack8(a, b);
        }
    }

    float pred0 = 0.f, pred1 = 0.f;
    int p = 0;
    __syncthreads();   // drains: stage(e0), pkhs, x loads

    for (int e = 0; e < NE; ++e) {
        const int e8 = e * 8;
        if (e < 7) {   // stage next expert into other buffer (drained at barrier)
            const char* src = (const char*)wfr + (size_t)(e + 1) * 65536
                            + (size_t)wid * 8192 + lane * 16;
            char* dst = (char*)&W1s[p ^ 1][0] + wid * 8192;
            #pragma unroll
            for (int i = 0; i < 8; ++i)
                __builtin_amdgcn_global_load_lds(
                    (const __attribute__((address_space(1))) unsigned int*)(src + i * 1024),
                    (__attribute__((address_space(3))) unsigned int*)(dst + i * 1024),
                    16, 0, 0);
        }

        // hoisted per-expert scalars (latency hides under MFMA stream)
        float gt0 = gates[(size_t)(tw + col) * NE + e];
        float gt1 = gates[(size_t)(tw + 32 + col) * NE + e];
        float bb  = b2[e];

        // rotated hrt order: wave w starts at hrt=rot (convoy-breaking)
        const int h0 = rot;
        const int h1 = (rot + 1) & 7;
        const int h2 = (rot + 2) & 7;
        const int h3 = (rot + 3) & 7;
        const int h4 = (rot + 4) & 7;
        const int h5 = (rot + 5) & 7;
        const int h6 = (rot + 6) & 7;
        const int h7 = (rot + 7) & 7;

        float ye0 = 0.f, ye1 = 0.f;
        f32x16 a0, a1, c0, c1;

        a0 = (f32x16)0.0f; a1 = (f32x16)0.0f;
        STEP_NOEPI(h0, a0, a1)
        c0 = (f32x16)0.0f; c1 = (f32x16)0.0f;
        STEP(h1, c0, c1, a0, a1, h0)
        a0 = (f32x16)0.0f; a1 = (f32x16)0.0f;
        STEP(h2, a0, a1, c0, c1, h1)
        c0 = (f32x16)0.0f; c1 = (f32x16)0.0f;
        STEP(h3, c0, c1, a0, a1, h2)
        a0 = (f32x16)0.0f; a1 = (f32x16)0.0f;
        STEP(h4, a0, a1, c0, c1, h3)
        c0 = (f32x16)0.0f; c1 = (f32x16)0.0f;
        STEP(h5, c0, c1, a0, a1, h4)
        a0 = (f32x16)0.0f; a1 = (f32x16)0.0f;
        STEP(h6, a0, a1, c0, c1, h5)
        c0 = (f32x16)0.0f; c1 = (f32x16)0.0f;
        STEP(h7, c0, c1, a0, a1, h6)
        EPI_TAIL(c0, c1, h7)

        // fold halves, sigmoid, gate-weight
        {
            float s0 = ye0 + __shfl_xor(ye0, 32, 64) + bb;
            float s1 = ye1 + __shfl_xor(ye1, 32, 64) + bb;
            float yv0 = 1.f / (1.f + __expf(-s0));
            float yv1 = 1.f / (1.f + __expf(-s1));
            pred0 = fmaf(gt0, yv0, pred0);
            pred1 = fmaf(gt1, yv1, pred1);
        }

        __syncthreads();   // buf[p] reads done; stage(e+1) drained
        p ^= 1;
    }

    if (lane < 32) {
        pred_out[tw + col]      = pred0;
        pred_out[tw + 32 + col] = pred1;
    }
}

// ---------------------------------------------------------------------------
extern "C" void kernel_launch(void* const* d_in, const int* in_sizes, int n_in,
                              void* d_out, int out_size, void* d_ws, size_t ws_size,
                              hipStream_t stream) {
    (void)in_sizes; (void)n_in; (void)out_size; (void)ws_size;
    const float* x  = (const float*)d_in[0];
    const float* cp = (const float*)d_in[1];
    const float* W1 = (const float*)d_in[2];
    const float* b1 = (const float*)d_in[3];
    const float* W2 = (const float*)d_in[4];
    const float* b2 = (const float*)d_in[5];

    float* out   = (float*)d_out;
    float* pred  = out;                       // [131072]
    float* gates = out + 131072;              // [131072*8]
    float* used  = out + 1179648;             // [131072]
    float* inf   = out + 1310720;             // [8]
    float* cnt   = out + 1310728;             // [8]

    unsigned short* wfrag = (unsigned short*)d_ws;            // 512 KB frag W1
    unsigned short* pkh = (unsigned short*)((char*)d_ws + 524288);  // 8 KB bf16 b1/w2
    float* part = (float*)((char*)d_ws + 532480);             // 32 KB partials

    prep_w1<<<dim3(1025), dim3(256), 0, stream>>>(W1, b1, W2, wfrag, pkh);
    gates_kernel<<<dim3(512), dim3(256), 0, stream>>>(cp, gates, used, part);
    reduce_kernel<<<dim3(1), dim3(512), 0, stream>>>(part, inf, cnt);
    moe_main<<<dim3(256), dim3(512), 0, stream>>>(x, wfrag, pkh, b2, gates, pred);
}